// Round 16
// baseline (150.694 us; speedup 1.0000x reference)
//
#include <hip/hip_runtime.h>
#include <hip/hip_bf16.h>

#define B_ 8
#define S_ 4096
#define Q_ 4096
#define D_ 64

typedef __attribute__((ext_vector_type(8))) short short8;
typedef __attribute__((ext_vector_type(4))) float f32x4;
typedef __attribute__((ext_vector_type(4), aligned(4))) float f32x4u;

__device__ __forceinline__ unsigned short f2bf(float f) {
  union { float f; unsigned u; } v; v.f = f;
  unsigned u = v.u;
  u += 0x7FFFu + ((u >> 16) & 1u);   // RNE (no NaN in inputs)
  return (unsigned short)(u >> 16);
}

// Convert query to bf16; convert support to bf16 PRE-SCALED by its rsqrt
// magnitude (folds the cosine normalization into the operand).
__global__ void prep_kernel(const float* __restrict__ supp,
                            const float* __restrict__ query,
                            unsigned short* __restrict__ supp_bf,
                            unsigned short* __restrict__ query_bf) {
  int r = blockIdx.x * blockDim.x + threadIdx.x;
  const int nsupp = B_ * S_;
  const int total = nsupp + B_ * Q_;
  if (r >= total) return;
  const bool is_supp = r < nsupp;
  const float* src = is_supp ? (supp + (size_t)r * D_)
                             : (query + (size_t)(r - nsupp) * D_);
  unsigned short* dst = is_supp ? (supp_bf + (size_t)r * D_)
                                : (query_bf + (size_t)(r - nsupp) * D_);
  float4 v[D_ / 4];
  float sum = 0.f;
#pragma unroll
  for (int i = 0; i < D_ / 4; ++i) {
    v[i] = ((const float4*)src)[i];
    sum += v[i].x * v[i].x + v[i].y * v[i].y + v[i].z * v[i].z + v[i].w * v[i].w;
  }
  const float sc = is_supp ? rsqrtf(fmaxf(sum, 1e-10f)) : 1.0f;
#pragma unroll
  for (int i = 0; i < D_ / 4; ++i) {
    ushort4 h;
    h.x = f2bf(v[i].x * sc); h.y = f2bf(v[i].y * sc);
    h.z = f2bf(v[i].z * sc); h.w = f2bf(v[i].w * sc);
    ((ushort4*)dst)[i] = h;
  }
}

// Branchless sorted-descending top-5 insert: 9 min/max ops.
__device__ __forceinline__ void ins5(float (&t)[5], float v) {
  float a = v, b;
  b = fminf(t[0], a); t[0] = fmaxf(t[0], a); a = b;
  b = fminf(t[1], a); t[1] = fmaxf(t[1], a); a = b;
  b = fminf(t[2], a); t[2] = fmaxf(t[2], a); a = b;
  b = fminf(t[3], a); t[3] = fmaxf(t[3], a); a = b;
  t[4] = fmaxf(t[4], a);
}

// LDS-ordering-only barrier (R11): ds ops drained, global stores in flight.
__device__ __forceinline__ void lds_barrier() {
  asm volatile("s_waitcnt lgkmcnt(0)" ::: "memory");
  __builtin_amdgcn_s_barrier();
}

// R15 + NONTEMPORAL copy stores (1-line probe): the 269 MB write-allocate
// stream sweeps each XCD L2 every ~1.2 µs, evicting staged support between
// reuses (why staging misses to HBM; why R14 swizzle only bought +2.3 µs).
// nt stores don't displace L2 -> support stays resident. R4's nt disaster
// was 64 B fragments; these are 256 B contiguous per quarter-wave.
__global__ void cos_topk_kernel(const unsigned short* __restrict__ supp_bf,
                                const unsigned short* __restrict__ query_bf,
                                const int* __restrict__ pbshot,
                                float* __restrict__ out) {
  const int bs = *pbshot;
  const int OW = 5 + S_ - bs;  // output row width

  const int x  = blockIdx.x;
  const int b  = x & 7;                  // batch == XCD id
  const int q0 = (x >> 3) * 64;
  const int tid  = threadIdx.x;
  const int w    = tid >> 6;
  const int lane = tid & 63;
  const int l15  = lane & 15;
  const int l4   = lane >> 4;

  const int nt_top = bs >> 6;
  const int role = blockIdx.y;
  const bool is_top = (role == 0);
  int t0, t1;
  if (is_top) { t0 = 0; t1 = nt_top; }
  else {
    const int ct = (S_ >> 6) - nt_top;
    t0 = nt_top + (ct * (role - 1)) / 6;
    t1 = nt_top + (ct * role) / 6;
  }

  __shared__ unsigned short lds[2][64 * 64];  // staging: 2 x 8 KB, swizzled
  __shared__ float elds[4][16][68];           // epilogue transpose, per-wave

  // --- A fragments: this wave's 16 query rows, K=64, held in regs ---
  // A layout (16x16x32): row = lane&15, k = (lane>>4)*8 + j
  const int qrow = q0 + w * 16 + l15;
  const unsigned short* qbase = query_bf + (size_t)(b * Q_ + qrow) * D_;
  const short8 a0 = *(const short8*)(qbase + l4 * 8);
  const short8 a1 = *(const short8*)(qbase + 32 + l4 * 8);

  float tk[4][5];
#pragma unroll
  for (int r2 = 0; r2 < 4; ++r2)
#pragma unroll
    for (int j = 0; j < 5; ++j) tk[r2][j] = -INFINITY;

  // --- staging (register path): 256 threads x 32B = one 8 KB tile ---
  const int srow  = tid >> 2;   // support row within tile
  const int chunk = tid & 3;    // 16-ushort chunk
  const unsigned short* gstage0 =
      supp_bf + ((size_t)b * S_ + srow) * D_ + chunk * 16;
  // swizzle invariant: LDS[r][c8] = G[r][c8 ^ (r&7)] in 8-ushort chunks
  const int dsw0 = srow * 64 + ((chunk * 16 + 0) ^ ((srow & 7) << 3));
  const int dsw1 = srow * 64 + ((chunk * 16 + 8) ^ ((srow & 7) << 3));

  uint4 st0 = *(const uint4*)(gstage0 + (size_t)t0 * 64 * D_);
  uint4 st1 = *(const uint4*)(gstage0 + (size_t)t0 * 64 * D_ + 8);
  *(uint4*)&lds[0][dsw0] = st0;
  *(uint4*)&lds[0][dsw1] = st1;

  const int rbase = b * Q_ + q0 + w * 16 + l4 * 4;        // top-k row base
  // copy-role epilogue base: wave's first q-row
  float* owave = out + (size_t)(b * Q_ + q0 + w * 16) * OW + 5 - bs;

  for (int t = t0; t < t1; ++t) {
    const int buf = (t - t0) & 1;
    if (t + 1 < t1) {  // issue next tile's global loads early (hide HBM lat)
      const unsigned short* g = gstage0 + (size_t)(t + 1) * 64 * D_;
      st0 = *(const uint4*)(g);
      st1 = *(const uint4*)(g + 8);
    }
    lds_barrier();     // tile t's ds_writes visible; stores stay in flight

    f32x4 ab[4];       // per-fc results (fully unrolled -> registers)
#pragma unroll
    for (int fc = 0; fc < 4; ++fc) {
      // B layout (16x16x32): col = lane&15, k = (lane>>4)*8 + j
      const int scol = fc * 16 + l15;  // support row within LDS tile
      const int idx0 = scol * 64 + ((l4 * 8) ^ ((scol & 7) << 3));
      const int idx1 = scol * 64 + ((32 + l4 * 8) ^ ((scol & 7) << 3));
      const short8 b0 = *(const short8*)&lds[buf][idx0];
      const short8 b1 = *(const short8*)&lds[buf][idx1];
      f32x4 acc = {0.f, 0.f, 0.f, 0.f};
      acc = __builtin_amdgcn_mfma_f32_16x16x32_bf16(a0, b0, acc, 0, 0, 0);
      acc = __builtin_amdgcn_mfma_f32_16x16x32_bf16(a1, b1, acc, 0, 0, 0);

      if (is_top) {
#pragma unroll
        for (int r2 = 0; r2 < 4; ++r2) ins5(tk[r2], acc[r2]);
      } else {
        ab[fc] = acc;
      }
    }

    if (!is_top) {
      // per-wave transpose write: [q-row within 16][s-col within 64]
#pragma unroll
      for (int fc = 0; fc < 4; ++fc)
#pragma unroll
        for (int r2 = 0; r2 < 4; ++r2)
          elds[w][l4 * 4 + r2][fc * 16 + l15] = ab[fc][r2];
      // vector read-back: 4 rows per pass, 4 consecutive cols per lane
#pragma unroll
      for (int pass = 0; pass < 4; ++pass) {
        const int i  = pass * 4 + l4;        // q-row within 16
        const int cc = l15 * 4;              // col group
        const f32x4 vv = *(const f32x4*)&elds[w][i][cc];   // ds_read_b128
        __builtin_nontemporal_store(
            (f32x4u)vv, (f32x4u*)(owave + (size_t)i * OW + t * 64 + cc));
      }
    }

    if (t + 1 < t1) {  // write next tile into the other buffer
      *(uint4*)&lds[buf ^ 1][dsw0] = st0;
      *(uint4*)&lds[buf ^ 1][dsw1] = st1;
    }
  }

  if (is_top) {
    // butterfly merge of top-5 across the 16 lanes sharing each row
#pragma unroll
    for (int m = 1; m <= 8; m <<= 1) {
#pragma unroll
      for (int r2 = 0; r2 < 4; ++r2) {
        float o0 = __shfl_xor(tk[r2][0], m);
        float o1 = __shfl_xor(tk[r2][1], m);
        float o2 = __shfl_xor(tk[r2][2], m);
        float o3 = __shfl_xor(tk[r2][3], m);
        float o4 = __shfl_xor(tk[r2][4], m);
        ins5(tk[r2], o0); ins5(tk[r2], o1); ins5(tk[r2], o2);
        ins5(tk[r2], o3); ins5(tk[r2], o4);
      }
    }
    if (l15 == 0) {
#pragma unroll
      for (int r2 = 0; r2 < 4; ++r2) {
        float* op = out + (size_t)(rbase + r2) * OW;
        op[0] = tk[r2][0]; op[1] = tk[r2][1]; op[2] = tk[r2][2];
        op[3] = tk[r2][3]; op[4] = tk[r2][4];
      }
    }
  }
}

extern "C" void kernel_launch(void* const* d_in, const int* in_sizes, int n_in,
                              void* d_out, int out_size, void* d_ws, size_t ws_size,
                              hipStream_t stream) {
  const float* supp  = (const float*)d_in[0];
  const float* query = (const float*)d_in[1];
  const int* pbshot  = (const int*)d_in[2];
  float* out = (float*)d_out;

  unsigned short* supp_bf  = (unsigned short*)d_ws;
  unsigned short* query_bf = supp_bf + (size_t)B_ * S_ * D_;

  const int rows = B_ * (S_ + Q_);
  prep_kernel<<<(rows + 255) / 256, 256, 0, stream>>>(supp, query, supp_bf,
                                                      query_bf);
  dim3 grid(B_ * (Q_ / 64), 7);
  cos_topk_kernel<<<grid, 256, 0, stream>>>(supp_bf, query_bf, pbshot, out);
}

// Round 17
// 76.693 us; speedup vs baseline: 1.9649x; 1.9649x over previous
//
#include <hip/hip_runtime.h>
#include <hip/hip_bf16.h>

#define B_ 8
#define S_ 4096
#define Q_ 4096
#define D_ 64

typedef __attribute__((ext_vector_type(8))) short short8;
typedef __attribute__((ext_vector_type(4))) float f32x4;
typedef __attribute__((ext_vector_type(4), aligned(4))) float f32x4u;

__device__ __forceinline__ unsigned short f2bf(float f) {
  union { float f; unsigned u; } v; v.f = f;
  unsigned u = v.u;
  u += 0x7FFFu + ((u >> 16) & 1u);   // RNE (no NaN in inputs)
  return (unsigned short)(u >> 16);
}

// Convert query to bf16; convert support to bf16 PRE-SCALED by its rsqrt
// magnitude (folds the cosine normalization into the operand).
__global__ void prep_kernel(const float* __restrict__ supp,
                            const float* __restrict__ query,
                            unsigned short* __restrict__ supp_bf,
                            unsigned short* __restrict__ query_bf) {
  int r = blockIdx.x * blockDim.x + threadIdx.x;
  const int nsupp = B_ * S_;
  const int total = nsupp + B_ * Q_;
  if (r >= total) return;
  const bool is_supp = r < nsupp;
  const float* src = is_supp ? (supp + (size_t)r * D_)
                             : (query + (size_t)(r - nsupp) * D_);
  unsigned short* dst = is_supp ? (supp_bf + (size_t)r * D_)
                                : (query_bf + (size_t)(r - nsupp) * D_);
  float4 v[D_ / 4];
  float sum = 0.f;
#pragma unroll
  for (int i = 0; i < D_ / 4; ++i) {
    v[i] = ((const float4*)src)[i];
    sum += v[i].x * v[i].x + v[i].y * v[i].y + v[i].z * v[i].z + v[i].w * v[i].w;
  }
  const float sc = is_supp ? rsqrtf(fmaxf(sum, 1e-10f)) : 1.0f;
#pragma unroll
  for (int i = 0; i < D_ / 4; ++i) {
    ushort4 h;
    h.x = f2bf(v[i].x * sc); h.y = f2bf(v[i].y * sc);
    h.z = f2bf(v[i].z * sc); h.w = f2bf(v[i].w * sc);
    ((ushort4*)dst)[i] = h;
  }
}

// Branchless sorted-descending top-5 insert: 9 min/max ops.
__device__ __forceinline__ void ins5(float (&t)[5], float v) {
  float a = v, b;
  b = fminf(t[0], a); t[0] = fmaxf(t[0], a); a = b;
  b = fminf(t[1], a); t[1] = fmaxf(t[1], a); a = b;
  b = fminf(t[2], a); t[2] = fmaxf(t[2], a); a = b;
  b = fminf(t[3], a); t[3] = fmaxf(t[3], a); a = b;
  t[4] = fmaxf(t[4], a);
}

// LDS-ordering-only barrier (R11): ds ops drained, global stores in flight.
__device__ __forceinline__ void lds_barrier() {
  asm volatile("s_waitcnt lgkmcnt(0)" ::: "memory");
  __builtin_amdgcn_s_barrier();
}

// R15 structure widened to 128 q-rows per block (8 waves, 512 threads):
// each staged support tile now serves 128 q-rows -> staging VMEM traffic
// halves (262->131 MB); LDS ~50 KB -> 3 blocks/CU = 24 waves/CU (was 16);
// staging is one uint4 + one ds_write_b128 per thread. Store path, swizzle,
// epilogue, role split: identical to R15 (proven).
__global__ __launch_bounds__(512) void
cos_topk_kernel(const unsigned short* __restrict__ supp_bf,
                const unsigned short* __restrict__ query_bf,
                const int* __restrict__ pbshot,
                float* __restrict__ out) {
  const int bs = *pbshot;
  const int OW = 5 + S_ - bs;  // output row width

  const int x  = blockIdx.x;
  const int b  = x & 7;                  // batch == XCD id (R14 swizzle)
  const int q0 = (x >> 3) * 128;         // 32 q-groups of 128 rows
  const int tid  = threadIdx.x;
  const int w    = tid >> 6;             // wave 0..7
  const int lane = tid & 63;
  const int l15  = lane & 15;
  const int l4   = lane >> 4;

  const int nt_top = bs >> 6;
  const int role = blockIdx.y;
  const bool is_top = (role == 0);
  int t0, t1;
  if (is_top) { t0 = 0; t1 = nt_top; }
  else {
    const int ct = (S_ >> 6) - nt_top;
    t0 = nt_top + (ct * (role - 1)) / 6;
    t1 = nt_top + (ct * role) / 6;
  }

  __shared__ unsigned short lds[2][64 * 64];  // staging: 2 x 8 KB, swizzled
  __shared__ float elds[8][16][68];           // epilogue transpose, per-wave

  // --- A fragments: this wave's 16 query rows, K=64, held in regs ---
  // A layout (16x16x32): row = lane&15, k = (lane>>4)*8 + j
  const int qrow = q0 + w * 16 + l15;
  const unsigned short* qbase = query_bf + (size_t)(b * Q_ + qrow) * D_;
  const short8 a0 = *(const short8*)(qbase + l4 * 8);
  const short8 a1 = *(const short8*)(qbase + 32 + l4 * 8);

  float tk[4][5];
#pragma unroll
  for (int r2 = 0; r2 < 4; ++r2)
#pragma unroll
    for (int j = 0; j < 5; ++j) tk[r2][j] = -INFINITY;

  // --- staging: 512 threads x 16B = one 8 KB tile ---
  const int srow  = tid >> 3;   // support row within tile (0..63)
  const int chunk = tid & 7;    // 8-ushort chunk
  const unsigned short* gstage0 =
      supp_bf + ((size_t)b * S_ + srow) * D_ + chunk * 8;
  // swizzle invariant: LDS[r][c8] = G[r][c8 ^ (r&7)] in 8-ushort chunks
  const int dsw = srow * 64 + ((chunk * 8) ^ ((srow & 7) << 3));

  uint4 st0 = *(const uint4*)(gstage0 + (size_t)t0 * 64 * D_);
  *(uint4*)&lds[0][dsw] = st0;

  const int rbase = b * Q_ + q0 + w * 16 + l4 * 4;        // top-k row base
  // copy-role epilogue base: wave's first q-row
  float* owave = out + (size_t)(b * Q_ + q0 + w * 16) * OW + 5 - bs;

  for (int t = t0; t < t1; ++t) {
    const int buf = (t - t0) & 1;
    if (t + 1 < t1) {  // issue next tile's global load early (hide HBM lat)
      st0 = *(const uint4*)(gstage0 + (size_t)(t + 1) * 64 * D_);
    }
    lds_barrier();     // tile t's ds_writes visible; stores stay in flight

    f32x4 ab[4];       // per-fc results (fully unrolled -> registers)
#pragma unroll
    for (int fc = 0; fc < 4; ++fc) {
      // B layout (16x16x32): col = lane&15, k = (lane>>4)*8 + j
      const int scol = fc * 16 + l15;  // support row within LDS tile
      const int idx0 = scol * 64 + ((l4 * 8) ^ ((scol & 7) << 3));
      const int idx1 = scol * 64 + ((32 + l4 * 8) ^ ((scol & 7) << 3));
      const short8 b0 = *(const short8*)&lds[buf][idx0];
      const short8 b1 = *(const short8*)&lds[buf][idx1];
      f32x4 acc = {0.f, 0.f, 0.f, 0.f};
      acc = __builtin_amdgcn_mfma_f32_16x16x32_bf16(a0, b0, acc, 0, 0, 0);
      acc = __builtin_amdgcn_mfma_f32_16x16x32_bf16(a1, b1, acc, 0, 0, 0);

      if (is_top) {
#pragma unroll
        for (int r2 = 0; r2 < 4; ++r2) ins5(tk[r2], acc[r2]);
      } else {
        ab[fc] = acc;
      }
    }

    if (!is_top) {
      // per-wave transpose write: [q-row within 16][s-col within 64]
#pragma unroll
      for (int fc = 0; fc < 4; ++fc)
#pragma unroll
        for (int r2 = 0; r2 < 4; ++r2)
          elds[w][l4 * 4 + r2][fc * 16 + l15] = ab[fc][r2];
      // vector read-back: 4 rows per pass, 4 consecutive cols per lane
#pragma unroll
      for (int pass = 0; pass < 4; ++pass) {
        const int i  = pass * 4 + l4;        // q-row within 16
        const int cc = l15 * 4;              // col group
        const f32x4 vv = *(const f32x4*)&elds[w][i][cc];   // ds_read_b128
        *(f32x4u*)(owave + (size_t)i * OW + t * 64 + cc) = vv;
      }
    }

    if (t + 1 < t1) {  // write next tile into the other buffer
      *(uint4*)&lds[buf ^ 1][dsw] = st0;
    }
  }

  if (is_top) {
    // butterfly merge of top-5 across the 16 lanes sharing each row
#pragma unroll
    for (int m = 1; m <= 8; m <<= 1) {
#pragma unroll
      for (int r2 = 0; r2 < 4; ++r2) {
        float o0 = __shfl_xor(tk[r2][0], m);
        float o1 = __shfl_xor(tk[r2][1], m);
        float o2 = __shfl_xor(tk[r2][2], m);
        float o3 = __shfl_xor(tk[r2][3], m);
        float o4 = __shfl_xor(tk[r2][4], m);
        ins5(tk[r2], o0); ins5(tk[r2], o1); ins5(tk[r2], o2);
        ins5(tk[r2], o3); ins5(tk[r2], o4);
      }
    }
    if (l15 == 0) {
#pragma unroll
      for (int r2 = 0; r2 < 4; ++r2) {
        float* op = out + (size_t)(rbase + r2) * OW;
        op[0] = tk[r2][0]; op[1] = tk[r2][1]; op[2] = tk[r2][2];
        op[3] = tk[r2][3]; op[4] = tk[r2][4];
      }
    }
  }
}

extern "C" void kernel_launch(void* const* d_in, const int* in_sizes, int n_in,
                              void* d_out, int out_size, void* d_ws, size_t ws_size,
                              hipStream_t stream) {
  const float* supp  = (const float*)d_in[0];
  const float* query = (const float*)d_in[1];
  const int* pbshot  = (const int*)d_in[2];
  float* out = (float*)d_out;

  unsigned short* supp_bf  = (unsigned short*)d_ws;
  unsigned short* query_bf = supp_bf + (size_t)B_ * S_ * D_;

  const int rows = B_ * (S_ + Q_);
  prep_kernel<<<(rows + 255) / 256, 256, 0, stream>>>(supp, query, supp_bf,
                                                      query_bf);
  dim3 grid(B_ * (Q_ / 128), 7);
  cos_topk_kernel<<<grid, 512, 0, stream>>>(supp_bf, query_bf, pbshot, out);
}